// Round 10
// baseline (18426.337 us; speedup 1.0000x reference)
//
#include <hip/hip_runtime.h>
#include <cmath>

#define SEQ 4096
#define INP 457
#define EMB 2048
#define NWG_E 256   // encoder: 1 WG (512 thr) per CU
#define NWG_D 16    // decoder: 16 WGs x 32 c-indices = 512 >= 457
#define NCPY 8      // enc h-ring replication factor
#define NDCPY 4     // dec hraw-ring replication factor

typedef unsigned long long u64t;
typedef float f32x4 __attribute__((ext_vector_type(4)));
typedef float f32x2 __attribute__((ext_vector_type(2)));

// Fast activations: v_exp + v_rcp. Saturation exact (rcp(inf)=0).
__device__ __forceinline__ float sigf(float v) {
  return __builtin_amdgcn_rcpf(1.0f + __expf(-v));
}
__device__ __forceinline__ float tanhf_fast(float v) {
  return 1.0f - 2.0f * __builtin_amdgcn_rcpf(__expf(2.0f * v) + 1.0f);
}

#define PIN(v) asm volatile("" : "+v"(v))
#define QNAN __builtin_bit_cast(float, 0x7fc00000u)

// MALL-coherent loads (bypass L1+L2). Manual vmcnt(0): compiler can't see these are loads.
__device__ __forceinline__ f32x4 mall16(const f32x4* p) {
  f32x4 v;
  asm volatile("global_load_dwordx4 %0, %1, off sc0 sc1\n\ts_waitcnt vmcnt(0)"
               : "=v"(v) : "v"(p) : "memory");
  return v;
}
__device__ __forceinline__ f32x2 mall8(const f32x2* p) {
  f32x2 v;
  asm volatile("global_load_dwordx2 %0, %1, off sc0 sc1\n\ts_waitcnt vmcnt(0)"
               : "=v"(v) : "v"(p) : "memory");
  return v;
}

// ---------------- bias precompute ----------------
__global__ void bias_kernel(const float* __restrict__ ebih, const float* __restrict__ ebhh,
                            const float* __restrict__ dbih, const float* __restrict__ dbhh,
                            float* __restrict__ bsum, float* __restrict__ btot) {
  int i = blockIdx.x * 256 + threadIdx.x;
  if (i < 4 * EMB) bsum[i] = ebih[i] + ebhh[i];
  if (i < 4 * INP) btot[i] = dbih[i] + dbhh[i];
}

// ---------------- Wfold = (dec_Wih + dec_Whh) @ dec_Whr  (1828 x 480, pad cols zero) ----------------
__global__ __launch_bounds__(256) void fold_gemm(const float* __restrict__ dWih,
                                                 const float* __restrict__ dWhh,
                                                 const float* __restrict__ dWhr,
                                                 float* __restrict__ C) {
  const int bx = blockIdx.x, by = blockIdx.y;
  const int tid = threadIdx.x;
  const int tx = tid & 15, ty = tid >> 4;
  __shared__ float As[16][65];
  __shared__ float Bs[16][65];
  float acc[4][4] = {};
  for (int k0 = 0; k0 < EMB; k0 += 16) {
#pragma unroll
    for (int e = 0; e < 4; ++e) {
      int eid = tid * 4 + e;
      int m = eid >> 4, k = eid & 15;
      int row = by * 64 + m;
      float v = 0.0f;
      if (row < 4 * INP) {
        size_t a = (size_t)row * EMB + k0 + k;
        v = dWih[a] + dWhh[a];
      }
      As[k][m] = v;
    }
#pragma unroll
    for (int e = 0; e < 4; ++e) {
      int eid = tid * 4 + e;
      int k = eid >> 6, c = eid & 63;
      int col = bx * 64 + c;
      Bs[k][c] = (col < INP) ? dWhr[(size_t)(k0 + k) * INP + col] : 0.0f;
    }
    __syncthreads();
#pragma unroll
    for (int k = 0; k < 16; ++k) {
      float a0 = As[k][ty * 4 + 0], a1 = As[k][ty * 4 + 1], a2 = As[k][ty * 4 + 2], a3 = As[k][ty * 4 + 3];
      float b0 = Bs[k][tx * 4 + 0], b1 = Bs[k][tx * 4 + 1], b2 = Bs[k][tx * 4 + 2], b3 = Bs[k][tx * 4 + 3];
      acc[0][0] += a0 * b0; acc[0][1] += a0 * b1; acc[0][2] += a0 * b2; acc[0][3] += a0 * b3;
      acc[1][0] += a1 * b0; acc[1][1] += a1 * b1; acc[1][2] += a1 * b2; acc[1][3] += a1 * b3;
      acc[2][0] += a2 * b0; acc[2][1] += a2 * b1; acc[2][2] += a2 * b2; acc[2][3] += a2 * b3;
      acc[3][0] += a3 * b0; acc[3][1] += a3 * b1; acc[3][2] += a3 * b2; acc[3][3] += a3 * b3;
    }
    __syncthreads();
  }
#pragma unroll
  for (int i = 0; i < 4; ++i) {
    int row = by * 64 + ty * 4 + i;
    if (row >= 4 * INP) continue;
#pragma unroll
    for (int j = 0; j < 4; ++j) {
      int col = bx * 64 + tx * 4 + j;
      if (col < 480) C[(size_t)row * 480 + col] = acc[i][j];
    }
  }
}

// ---------------- persistent encoder: R9 protocol + shfl exchange + x-MAC pre-poll ----------------
// 256 WGs x 512 thr. WG w owns h-indices [8w, 8w+8). Weights pinned in VGPRs (160 f/thread).
// Data-is-the-flag on a depth-4 x NCPY(8)-replicated hbuf ring (NaN = empty). Consumer WG
// polls only copy wg&7 (lane tid polls granule tid, SAME granule every step). Producers
// (wave0) publish/reset all 8 copies coalesced (32B/copy); deferred drain (vmcnt(0) is
// free, drains last step's stores) -> publish h(t+1) -> fire-and-forget resets of slot
// (t+3)&3. Per-granule visibility proof as R8/R9.
// NEW vs R9 (compute path only, sync byte-identical):
//  * x-part MAC BEFORE the poll: fills the dead window between barrier and h visibility,
//    so the first poll read lands after the publish instead of guaranteed-missing.
//  * Intra-8-lane-group __shfl exchange replaces hl4/xl4 LDS staging: lane (kc,j) needs
//    granules (l&~7)+q and x from lanes (l&~7)+i — all in its own group. Divergent-poll
//    reconvergence guarantees all source g4 registers are final. Identical FMA order.
__global__ __launch_bounds__(512) __attribute__((amdgpu_waves_per_eu(2, 2))) void enc_kernel(
    const float* __restrict__ x, const float* __restrict__ Wih,
    const float* __restrict__ Whh, const float* __restrict__ bsum,
    float* __restrict__ hbuf) {
  const int tid = threadIdx.x;
  const int wg  = blockIdx.x;
  const int j   = tid & 7;
  const int kc  = tid >> 3;            // 0..63
  const int jbase = wg * 8;
  const int mycpy = wg & (NCPY - 1);
  const int gb  = (tid & 63) & ~7;     // 8-lane group base (lane space)

  float wh[4][32];
  float wi[4][8];
#pragma unroll
  for (int g = 0; g < 4; ++g) {
    const size_t row = (size_t)(g * EMB + jbase + j);
    const float* wp = Whh + row * EMB + kc * 32;
#pragma unroll
    for (int q = 0; q < 8; ++q) {
      const float4 v = *(const float4*)(wp + 4 * q);
      wh[g][q * 4 + 0] = v.x; wh[g][q * 4 + 1] = v.y;
      wh[g][q * 4 + 2] = v.z; wh[g][q * 4 + 3] = v.w;
    }
    const float* ip = Wih + row * INP;
#pragma unroll
    for (int i = 0; i < 8; ++i) {
      const int c = kc * 8 + i;
      wi[g][i] = (c < INP) ? ip[c] : 0.0f;
    }
  }
#pragma unroll
  for (int g = 0; g < 4; ++g) {
#pragma unroll
    for (int q = 0; q < 32; ++q) PIN(wh[g][q]);
#pragma unroll
    for (int q = 0; q < 8; ++q) PIN(wi[g][q]);
  }
  const float bg0 = bsum[0 * EMB + jbase + j];
  const float bg1 = bsum[1 * EMB + jbase + j];
  const float bg2 = bsum[2 * EMB + jbase + j];
  const float bg3 = bsum[3 * EMB + jbase + j];
  float c_reg = 0.0f;

  __shared__ float partbuf[256];       // 8 waves x 8 j x 4 gates (only LDS left)
  const int xi = (tid < INP) ? tid : 0;

  for (int t = 0; t < SEQ; ++t) {
    // ---- x load + x-part MAC (pre-poll: overlaps the publish->visible window) ----
    const float xraw = x[(size_t)t * INP + xi];   // OOB lanes load x[0]; wi=0 masks them
    float4 a0 = make_float4(0, 0, 0, 0), a1 = a0, a2 = a0, a3 = a0;
#pragma unroll
    for (int q = 0; q < 2; ++q) {
      const float xv0 = __shfl(xraw, gb + q * 4 + 0);
      const float xv1 = __shfl(xraw, gb + q * 4 + 1);
      const float xv2 = __shfl(xraw, gb + q * 4 + 2);
      const float xv3 = __shfl(xraw, gb + q * 4 + 3);
      a0.x += wi[0][q * 4 + 0] * xv0; a0.y += wi[0][q * 4 + 1] * xv1; a0.z += wi[0][q * 4 + 2] * xv2; a0.w += wi[0][q * 4 + 3] * xv3;
      a1.x += wi[1][q * 4 + 0] * xv0; a1.y += wi[1][q * 4 + 1] * xv1; a1.z += wi[1][q * 4 + 2] * xv2; a1.w += wi[1][q * 4 + 3] * xv3;
      a2.x += wi[2][q * 4 + 0] * xv0; a2.y += wi[2][q * 4 + 1] * xv1; a2.z += wi[2][q * 4 + 2] * xv2; a2.w += wi[2][q * 4 + 3] * xv3;
      a3.x += wi[3][q * 4 + 0] * xv0; a3.y += wi[3][q * 4 + 1] * xv1; a3.z += wi[3][q * 4 + 2] * xv3 * 0.0f + wi[3][q * 4 + 2] * xv2; a3.w += wi[3][q * 4 + 3] * xv3;
    }

    // ---- poll own 16B granule of h_t in MY copy (NaN = not yet written) ----
    const f32x4* gp = (const f32x4*)(hbuf + (size_t)((t & 3) * NCPY + mycpy) * EMB) + tid;
    f32x4 g4;
    for (;;) {
      g4 = mall16(gp);
      if ((g4.x == g4.x) & (g4.y == g4.y) & (g4.z == g4.z) & (g4.w == g4.w)) break;
    }
    // reconvergence: every lane's g4 final here

    // ---- h-part MAC via intra-group shfl (granule gb+q == logical granule kc*8+q) ----
#pragma unroll
    for (int q = 0; q < 8; ++q) {
      f32x4 hv;
      hv.x = __shfl(g4.x, gb + q);
      hv.y = __shfl(g4.y, gb + q);
      hv.z = __shfl(g4.z, gb + q);
      hv.w = __shfl(g4.w, gb + q);
      const int b = q * 4;
      a0.x += wh[0][b + 0] * hv.x; a0.y += wh[0][b + 1] * hv.y; a0.z += wh[0][b + 2] * hv.z; a0.w += wh[0][b + 3] * hv.w;
      a1.x += wh[1][b + 0] * hv.x; a1.y += wh[1][b + 1] * hv.y; a1.z += wh[1][b + 2] * hv.z; a1.w += wh[1][b + 3] * hv.w;
      a2.x += wh[2][b + 0] * hv.x; a2.y += wh[2][b + 1] * hv.y; a2.z += wh[2][b + 2] * hv.z; a2.w += wh[2][b + 3] * hv.w;
      a3.x += wh[3][b + 0] * hv.x; a3.y += wh[3][b + 1] * hv.y; a3.z += wh[3][b + 2] * hv.z; a3.w += wh[3][b + 3] * hv.w;
    }

    // ---- reduce 8 kc-chunks inside each wave (lane bits 3,4,5), partials to LDS ----
    float r0 = (a0.x + a0.y) + (a0.z + a0.w);
    float r1 = (a1.x + a1.y) + (a1.z + a1.w);
    float r2 = (a2.x + a2.y) + (a2.z + a2.w);
    float r3 = (a3.x + a3.y) + (a3.z + a3.w);
#pragma unroll
    for (int m = 8; m < 64; m <<= 1) {
      r0 += __shfl_xor(r0, m); r1 += __shfl_xor(r1, m);
      r2 += __shfl_xor(r2, m); r3 += __shfl_xor(r3, m);
    }
    if ((tid & 63) < 8)
      *(float4*)(partbuf + (tid >> 6) * 32 + j * 4) = make_float4(r0, r1, r2, r3);
    __syncthreads();   // the ONLY per-step barrier

    // ---- wave0: gather, fast activate, [free drain] publish, deferred resets ----
    if (tid < 8) {
      float s0 = 0.f, s1 = 0.f, s2 = 0.f, s3 = 0.f;
#pragma unroll
      for (int w = 0; w < 8; ++w) {
        const float4 pv = *(const float4*)(partbuf + w * 32 + tid * 4);
        s0 += pv.x; s1 += pv.y; s2 += pv.z; s3 += pv.w;
      }
      const float gi = s0 + bg0, gf = s1 + bg1, gg = s2 + bg2, go = s3 + bg3;
      const float cN = sigf(gf) * c_reg + sigf(gi) * tanhf_fast(gg);
      c_reg = cN;
      const float hN = sigf(go) * tanhf_fast(cN);
      asm volatile("s_waitcnt vmcnt(0)" ::: "memory");   // drains last step's stores: free
      float* const pub = hbuf + (size_t)(((t + 1) & 3) * NCPY) * EMB + jbase + tid;
#pragma unroll
      for (int c = 0; c < NCPY; ++c)
        __hip_atomic_store(pub + (size_t)c * EMB, hN,
                           __ATOMIC_RELAXED, __HIP_MEMORY_SCOPE_AGENT);
      float* const rearm = hbuf + (size_t)(((t + 3) & 3) * NCPY) * EMB + jbase + tid;
#pragma unroll
      for (int c = 0; c < NCPY; ++c)
        __hip_atomic_store(rearm + (size_t)c * EMB, QNAN,
                           __ATOMIC_RELAXED, __HIP_MEMORY_SCOPE_AGENT);
    }
  }
}

// ---------------- persistent decoder: R9 protocol + shfl exchange + aligned poll ----------------
// 16 WGs x 512 thr. WG w owns c-indices [32w, 32w+32). Wfold 4x30 = 120 floats/thread pinned.
// hraw ring 4 slots x NDCPY(4) copies x 512 f32 (NaN = empty); consumer WG polls copy wg&3.
// NEW vs R9: only lanes l<30 of each wave poll (granule 30*wv+l; duplicates gone — poll
// traffic halved); MAC sources granules via __shfl from lanes (l>>5)*15+q (<30) after
// reconvergence. s_sleep(4) pre-poll aligns the first read with publish visibility
// (bounded cost ~256cy if a WG runs behind). Tail/publish/reset byte-identical to R9.
__global__ __launch_bounds__(512) __attribute__((amdgpu_waves_per_eu(2, 2))) void dec_kernel(
    const float* __restrict__ dWih, const float* __restrict__ Wfold,
    const float* __restrict__ btot, const float* __restrict__ henc,
    float* __restrict__ hraw, float* __restrict__ out) {
  const int tid = threadIdx.x;
  const int wg  = blockIdx.x;
  const int j   = tid & 31;
  const int kc  = tid >> 5;          // 0..15 (wave v has kc in {2v, 2v+1})
  const int idx = wg * 32 + j;
  const bool valid = (idx < INP);
  const int id0 = valid ? idx : 0;
  const int l   = tid & 63;
  const int wv  = tid >> 6;
  const int mycpy = wg & (NDCPY - 1);

  float wd[4][30];
#pragma unroll
  for (int g = 0; g < 4; ++g) {
    const float* wp = Wfold + (size_t)(g * INP + id0) * 480 + kc * 30;
#pragma unroll
    for (int q = 0; q < 15; ++q) {
      const float2 v = valid ? *(const float2*)(wp + 2 * q) : make_float2(0.0f, 0.0f);
      wd[g][q * 2 + 0] = v.x; wd[g][q * 2 + 1] = v.y;
    }
  }
#pragma unroll
  for (int g = 0; g < 4; ++g)
#pragma unroll
    for (int q = 0; q < 30; ++q) PIN(wd[g][q]);

  const float bg0 = valid ? btot[0 * INP + idx] : 0.0f;
  const float bg1 = valid ? btot[1 * INP + idx] : 0.0f;
  const float bg2 = valid ? btot[2 * INP + idx] : 0.0f;
  const float bg3 = valid ? btot[3 * INP + idx] : 0.0f;
  float c_reg = 0.0f;

  __shared__ float partbuf[1024]; // 8 waves x 32 j x 4 gates (only LDS left)

  for (int t = 0; t < SEQ; ++t) {
    f32x2 g2 = {0.0f, 0.0f};
    if (t > 0) {
      __builtin_amdgcn_s_sleep(4);   // ~256cy: align first poll read with publish visibility
      if (l < 30) {
        const f32x2* gp = (const f32x2*)(hraw + (size_t)((t & 3) * NDCPY + mycpy) * 512)
                          + (30 * wv + l);
        for (;;) {
          g2 = mall8(gp);
          if ((g2.x == g2.x) & (g2.y == g2.y)) break;
        }
      }
      // reconvergence: lanes l<30 hold final granules 30*wv+l
    }

    float2 acc0 = make_float2(0, 0), acc1 = acc0, acc2 = acc0, acc3 = acc0;
    if (t == 0) {
      if (valid) {
#pragma unroll 4
        for (int q = 0; q < 32; ++q) {
          const float4 hv = *(const float4*)(henc + kc * 128 + 4 * q);
          const float4 w0 = *(const float4*)(dWih + (size_t)(0 * INP + idx) * EMB + kc * 128 + 4 * q);
          const float4 w1 = *(const float4*)(dWih + (size_t)(1 * INP + idx) * EMB + kc * 128 + 4 * q);
          const float4 w2 = *(const float4*)(dWih + (size_t)(2 * INP + idx) * EMB + kc * 128 + 4 * q);
          const float4 w3 = *(const float4*)(dWih + (size_t)(3 * INP + idx) * EMB + kc * 128 + 4 * q);
          acc0.x += w0.x * hv.x + w0.z * hv.z; acc0.y += w0.y * hv.y + w0.w * hv.w;
          acc1.x += w1.x * hv.x + w1.z * hv.z; acc1.y += w1.y * hv.y + w1.w * hv.w;
          acc2.x += w2.x * hv.x + w2.z * hv.z; acc2.y += w2.y * hv.y + w2.w * hv.w;
          acc3.x += w3.x * hv.x + w3.z * hv.z; acc3.y += w3.y * hv.y + w3.w * hv.w;
        }
      }
    } else {
      const int sb = (l >> 5) * 15;   // source-lane base for this lane's kc
#pragma unroll
      for (int q = 0; q < 15; ++q) {
        float2 hv;
        hv.x = __shfl(g2.x, sb + q);
        hv.y = __shfl(g2.y, sb + q);
        acc0.x += wd[0][q * 2] * hv.x; acc0.y += wd[0][q * 2 + 1] * hv.y;
        acc1.x += wd[1][q * 2] * hv.x; acc1.y += wd[1][q * 2 + 1] * hv.y;
        acc2.x += wd[2][q * 2] * hv.x; acc2.y += wd[2][q * 2 + 1] * hv.y;
        acc3.x += wd[3][q * 2] * hv.x; acc3.y += wd[3][q * 2 + 1] * hv.y;
      }
    }
    float r0 = acc0.x + acc0.y, r1 = acc1.x + acc1.y, r2 = acc2.x + acc2.y, r3 = acc3.x + acc3.y;
    r0 += __shfl_xor(r0, 32); r1 += __shfl_xor(r1, 32);
    r2 += __shfl_xor(r2, 32); r3 += __shfl_xor(r3, 32);
    if ((tid & 63) < 32)
      *(float4*)(partbuf + (tid >> 6) * 128 + (tid & 31) * 4) = make_float4(r0, r1, r2, r3);
    __syncthreads();   // the ONLY per-step barrier

    if (tid < 32) {
      const int ix = wg * 32 + tid;
      float s0 = 0.f, s1 = 0.f, s2 = 0.f, s3 = 0.f;
#pragma unroll
      for (int w = 0; w < 8; ++w) {
        const float4 pv = *(const float4*)(partbuf + w * 128 + tid * 4);
        s0 += pv.x; s1 += pv.y; s2 += pv.z; s3 += pv.w;
      }
      const float gi = s0 + bg0, gf = s1 + bg1, gg = s2 + bg2, go = s3 + bg3;
      const float cN = sigf(gf) * c_reg + sigf(gi) * tanhf_fast(gg);
      c_reg = cN;
      const float hrN = sigf(go) * tanhf_fast(cN);
      asm volatile("s_waitcnt vmcnt(0)" ::: "memory");   // drains last step's stores: free
      if (ix < 480) {
        const float pv = (ix < INP) ? hrN : 0.0f;
#pragma unroll
        for (int c = 0; c < NDCPY; ++c)
          __hip_atomic_store(hraw + (size_t)(((t + 1) & 3) * NDCPY + c) * 512 + ix, pv,
                             __ATOMIC_RELAXED, __HIP_MEMORY_SCOPE_AGENT);
      }
      if (ix < INP) out[(size_t)(SEQ - 1 - t) * INP + ix] = cN;
      if (ix < 480) {
#pragma unroll
        for (int c = 0; c < NDCPY; ++c)
          __hip_atomic_store(hraw + (size_t)(((t + 3) & 3) * NDCPY + c) * 512 + ix, QNAN,
                             __ATOMIC_RELAXED, __HIP_MEMORY_SCOPE_AGENT);
      }
    }
  }
}

// ---------------- row softmax in-place on d_out (4096 x 457) ----------------
__global__ __launch_bounds__(512) void softmax_kernel(float* __restrict__ out) {
  const int row = blockIdx.x;
  const int tid = threadIdx.x;
  __shared__ float red[512];
  float* rp = out + (size_t)row * INP;
  float v = (tid < INP) ? rp[tid] : -INFINITY;
  red[tid] = v;
  __syncthreads();
#pragma unroll
  for (int off = 256; off > 0; off >>= 1) {
    if (tid < off) red[tid] = fmaxf(red[tid], red[tid + off]);
    __syncthreads();
  }
  const float m = red[0];
  __syncthreads();
  const float e = (tid < INP) ? expf(v - m) : 0.0f;
  red[tid] = e;
  __syncthreads();
#pragma unroll
  for (int off = 256; off > 0; off >>= 1) {
    if (tid < off) red[tid] = red[tid] + red[tid + off];
    __syncthreads();
  }
  const float s = red[0];
  if (tid < INP) rp[tid] = e / s;
}

extern "C" void kernel_launch(void* const* d_in, const int* in_sizes, int n_in,
                              void* d_out, int out_size, void* d_ws, size_t ws_size,
                              hipStream_t stream) {
  const float* x    = (const float*)d_in[0];
  const float* eWih = (const float*)d_in[1];
  const float* eWhh = (const float*)d_in[2];
  const float* ebih = (const float*)d_in[3];
  const float* ebhh = (const float*)d_in[4];
  const float* dWih = (const float*)d_in[5];
  const float* dWhh = (const float*)d_in[6];
  const float* dbih = (const float*)d_in[7];
  const float* dbhh = (const float*)d_in[8];
  const float* dWhr = (const float*)d_in[9];
  float* out = (float*)d_out;
  char* ws = (char*)d_ws;

  // ws layout (same as R9):
  // [0, 262144):         hbuf ring: 4 slots x NCPY(8) copies x 2048 f32. Slot0 (all copies)
  //                      pre-zeroed = h_0; rest NaN. h_enc = h_4096 lands in slot0, copy0.
  // [262144, 294912):    hraw ring: 4 slots x NDCPY(4) copies x 512 f32, NaN-init.
  // [294912, 327680):    bsum (4*EMB f32)
  // [327680, 335872):    btot (4*INP f32, padded)
  // [335872, +3.51MB):   Wfold 1828x480
  float* hbuf  = (float*)(ws + 0);
  float* hraw  = (float*)(ws + 262144);
  float* bsum  = (float*)(ws + 294912);
  float* btot  = (float*)(ws + 327680);
  float* Wfold = (float*)(ws + 335872);

  hipMemsetAsync(ws, 0xFF, 294912, stream);   // hbuf (all slots/copies) + hraw -> NaN sentinel
  hipMemsetAsync(ws, 0x00, 65536, stream);    // hbuf slot0, all 8 copies -> h_0 = 0
  bias_kernel<<<40, 256, 0, stream>>>(ebih, ebhh, dbih, dbhh, bsum, btot);
  fold_gemm<<<dim3(8, 29), 256, 0, stream>>>(dWih, dWhh, dWhr, Wfold);
  enc_kernel<<<NWG_E, 512, 0, stream>>>(x, eWih, eWhh, bsum, hbuf);
  dec_kernel<<<NWG_D, 512, 0, stream>>>(dWih, Wfold, btot, hbuf, hraw, out);
  softmax_kernel<<<SEQ, 512, 0, stream>>>(out);
}

// Round 11
// 15396.729 us; speedup vs baseline: 1.1968x; 1.1968x over previous
//
#include <hip/hip_runtime.h>
#include <cmath>

#define SEQ 4096
#define INP 457
#define EMB 2048
#define NWG_E 256   // encoder: 1 WG (512 thr) per CU
#define NWG_D 16    // decoder: 16 WGs x 32 c-indices = 512 >= 457
#define NCPY 8      // enc h-ring replication factor
#define NDCPY 4     // dec hraw-ring replication factor

typedef unsigned long long u64t;
typedef float f32x4 __attribute__((ext_vector_type(4)));
typedef float f32x2 __attribute__((ext_vector_type(2)));

// Fast activations: v_exp + v_rcp. Saturation exact (rcp(inf)=0).
__device__ __forceinline__ float sigf(float v) {
  return __builtin_amdgcn_rcpf(1.0f + __expf(-v));
}
__device__ __forceinline__ float tanhf_fast(float v) {
  return 1.0f - 2.0f * __builtin_amdgcn_rcpf(__expf(2.0f * v) + 1.0f);
}

#define PIN(v) asm volatile("" : "+v"(v))
#define QNAN __builtin_bit_cast(float, 0x7fc00000u)

// MALL-coherent loads (bypass L1+L2). Manual vmcnt(0): compiler can't see these are loads.
__device__ __forceinline__ f32x4 mall16(const f32x4* p) {
  f32x4 v;
  asm volatile("global_load_dwordx4 %0, %1, off sc0 sc1\n\ts_waitcnt vmcnt(0)"
               : "=v"(v) : "v"(p) : "memory");
  return v;
}
__device__ __forceinline__ f32x2 mall8(const f32x2* p) {
  f32x2 v;
  asm volatile("global_load_dwordx2 %0, %1, off sc0 sc1\n\ts_waitcnt vmcnt(0)"
               : "=v"(v) : "v"(p) : "memory");
  return v;
}

// ---------------- bias precompute ----------------
__global__ void bias_kernel(const float* __restrict__ ebih, const float* __restrict__ ebhh,
                            const float* __restrict__ dbih, const float* __restrict__ dbhh,
                            float* __restrict__ bsum, float* __restrict__ btot) {
  int i = blockIdx.x * 256 + threadIdx.x;
  if (i < 4 * EMB) bsum[i] = ebih[i] + ebhh[i];
  if (i < 4 * INP) btot[i] = dbih[i] + dbhh[i];
}

// ---------------- Wfold = (dec_Wih + dec_Whh) @ dec_Whr  (1828 x 480, pad cols zero) ----------------
__global__ __launch_bounds__(256) void fold_gemm(const float* __restrict__ dWih,
                                                 const float* __restrict__ dWhh,
                                                 const float* __restrict__ dWhr,
                                                 float* __restrict__ C) {
  const int bx = blockIdx.x, by = blockIdx.y;
  const int tid = threadIdx.x;
  const int tx = tid & 15, ty = tid >> 4;
  __shared__ float As[16][65];
  __shared__ float Bs[16][65];
  float acc[4][4] = {};
  for (int k0 = 0; k0 < EMB; k0 += 16) {
#pragma unroll
    for (int e = 0; e < 4; ++e) {
      int eid = tid * 4 + e;
      int m = eid >> 4, k = eid & 15;
      int row = by * 64 + m;
      float v = 0.0f;
      if (row < 4 * INP) {
        size_t a = (size_t)row * EMB + k0 + k;
        v = dWih[a] + dWhh[a];
      }
      As[k][m] = v;
    }
#pragma unroll
    for (int e = 0; e < 4; ++e) {
      int eid = tid * 4 + e;
      int k = eid >> 6, c = eid & 63;
      int col = bx * 64 + c;
      Bs[k][c] = (col < INP) ? dWhr[(size_t)(k0 + k) * INP + col] : 0.0f;
    }
    __syncthreads();
#pragma unroll
    for (int k = 0; k < 16; ++k) {
      float a0 = As[k][ty * 4 + 0], a1 = As[k][ty * 4 + 1], a2 = As[k][ty * 4 + 2], a3 = As[k][ty * 4 + 3];
      float b0 = Bs[k][tx * 4 + 0], b1 = Bs[k][tx * 4 + 1], b2 = Bs[k][tx * 4 + 2], b3 = Bs[k][tx * 4 + 3];
      acc[0][0] += a0 * b0; acc[0][1] += a0 * b1; acc[0][2] += a0 * b2; acc[0][3] += a0 * b3;
      acc[1][0] += a1 * b0; acc[1][1] += a1 * b1; acc[1][2] += a1 * b2; acc[1][3] += a1 * b3;
      acc[2][0] += a2 * b0; acc[2][1] += a2 * b1; acc[2][2] += a2 * b2; acc[2][3] += a2 * b3;
      acc[3][0] += a3 * b0; acc[3][1] += a3 * b1; acc[3][2] += a3 * b2; acc[3][3] += a3 * b3;
    }
    __syncthreads();
  }
#pragma unroll
  for (int i = 0; i < 4; ++i) {
    int row = by * 64 + ty * 4 + i;
    if (row >= 4 * INP) continue;
#pragma unroll
    for (int j = 0; j < 4; ++j) {
      int col = bx * 64 + tx * 4 + j;
      if (col < 480) C[(size_t)row * 480 + col] = acc[i][j];
    }
  }
}

// ---------------- persistent encoder: R9 structure + x-prefetch + poll backoff ----------------
// 256 WGs x 512 thr. WG w owns h-indices [8w, 8w+8). Weights pinned in VGPRs (160 f/thread).
// Data-is-the-flag on a depth-4 x NCPY(8)-replicated hbuf ring (NaN = empty). Consumer WG
// polls only copy wg&7 (lane tid polls granule tid, SAME granule every step). Producers
// (wave0) publish/reset all 8 copies coalesced (32B/copy). Deferred drain: wave0 tail =
// vmcnt(0) [drains LAST step's stores -> free] -> publish h(t+1) -> fire-and-forget NaN
// resets of slot (t+3)&3. Per-granule visibility proof as R8/R9.
// NEW vs R9: x[t+1] prefetched BEFORE the poll (HBM latency overlaps poll RTT instead of
// sitting between poll-exit and the xl4 store); s_sleep(1) backoff after a missed poll
// (bounded +64cy detection latency, ~20% less poll traffic).
__global__ __launch_bounds__(512) __attribute__((amdgpu_waves_per_eu(2, 2))) void enc_kernel(
    const float* __restrict__ x, const float* __restrict__ Wih,
    const float* __restrict__ Whh, const float* __restrict__ bsum,
    float* __restrict__ hbuf) {
  const int tid = threadIdx.x;
  const int wg  = blockIdx.x;
  const int j   = tid & 7;
  const int kc  = tid >> 3;            // 0..63 (wave-local: wave w has kc in [8w, 8w+8))
  const int jbase = wg * 8;
  const int mycpy = wg & (NCPY - 1);

  float wh[4][32];
  float wi[4][8];
#pragma unroll
  for (int g = 0; g < 4; ++g) {
    const size_t row = (size_t)(g * EMB + jbase + j);
    const float* wp = Whh + row * EMB + kc * 32;
#pragma unroll
    for (int q = 0; q < 8; ++q) {
      const float4 v = *(const float4*)(wp + 4 * q);
      wh[g][q * 4 + 0] = v.x; wh[g][q * 4 + 1] = v.y;
      wh[g][q * 4 + 2] = v.z; wh[g][q * 4 + 3] = v.w;
    }
    const float* ip = Wih + row * INP;
#pragma unroll
    for (int i = 0; i < 8; ++i) {
      const int c = kc * 8 + i;
      wi[g][i] = (c < INP) ? ip[c] : 0.0f;
    }
  }
  // pin all 160 weight floats in VGPRs
#pragma unroll
  for (int g = 0; g < 4; ++g) {
#pragma unroll
    for (int q = 0; q < 32; ++q) PIN(wh[g][q]);
#pragma unroll
    for (int q = 0; q < 8; ++q) PIN(wi[g][q]);
  }
  // per-lane j biases + cell state in registers (used only by tid<8 in the tail)
  const float bg0 = bsum[0 * EMB + jbase + j];
  const float bg1 = bsum[1 * EMB + jbase + j];
  const float bg2 = bsum[2 * EMB + jbase + j];
  const float bg3 = bsum[3 * EMB + jbase + j];
  float c_reg = 0.0f;

  __shared__ float4 hl4[512];          // 8 KB: h_t, swizzled 16B granules, wave-local regions
  __shared__ float4 xl4[128];          // 2 KB: x_t (512 floats, pad 0), wave-local regions
  __shared__ float  partbuf[256];      // 8 waves x 8 j x 4 gates
  const int sw = kc & 7;
  const int hphys = tid ^ ((tid >> 3) & 7);   // write-side granule swizzle (stays in wave region)
  const int xi = (tid < INP) ? tid : 0;

  float xcur = x[xi];                  // x_0 prefetched

  for (int t = 0; t < SEQ; ++t) {
    // ---- prefetch x_{t+1} BEFORE the poll: HBM latency overlaps the poll RTT ----
    const int tn = (t + 1 < SEQ) ? t + 1 : t;
    float xnext = x[(size_t)tn * INP + xi];

    // ---- poll own 16B granule of h_t in MY copy (NaN = not yet written) ----
    const f32x4* gp = (const f32x4*)(hbuf + (size_t)((t & 3) * NCPY + mycpy) * EMB) + tid;
    f32x4 g4;
    for (;;) {
      g4 = mall16(gp);
      if ((g4.x == g4.x) & (g4.y == g4.y) & (g4.z == g4.z) & (g4.w == g4.w)) break;
      __builtin_amdgcn_s_sleep(1);   // 64cy backoff: bounded, cuts poll traffic
    }
    hl4[hphys] = make_float4(g4.x, g4.y, g4.z, g4.w);
    ((float*)xl4)[tid] = (tid < INP) ? xcur : 0.0f;
    // no barrier: same-wave DS ordering suffices (wave reads only its own region)

    // ---- MAC: 4 gates x (8 x + 32 h) ----
    float4 a0 = make_float4(0, 0, 0, 0), a1 = a0, a2 = a0, a3 = a0;
#pragma unroll
    for (int q = 0; q < 2; ++q) {
      const float4 xq = xl4[kc * 2 + q];
      a0.x += wi[0][q * 4 + 0] * xq.x; a0.y += wi[0][q * 4 + 1] * xq.y; a0.z += wi[0][q * 4 + 2] * xq.z; a0.w += wi[0][q * 4 + 3] * xq.w;
      a1.x += wi[1][q * 4 + 0] * xq.x; a1.y += wi[1][q * 4 + 1] * xq.y; a1.z += wi[1][q * 4 + 2] * xq.z; a1.w += wi[1][q * 4 + 3] * xq.w;
      a2.x += wi[2][q * 4 + 0] * xq.x; a2.y += wi[2][q * 4 + 1] * xq.y; a2.z += wi[2][q * 4 + 2] * xq.z; a2.w += wi[2][q * 4 + 3] * xq.w;
      a3.x += wi[3][q * 4 + 0] * xq.x; a3.y += wi[3][q * 4 + 1] * xq.y; a3.z += wi[3][q * 4 + 2] * xq.z; a3.w += wi[3][q * 4 + 3] * xq.w;
    }
#pragma unroll
    for (int q = 0; q < 8; ++q) {
      const float4 hv = hl4[kc * 8 + (q ^ sw)];   // holds LOGICAL granule kc*8+q
      const int b = q * 4;
      a0.x += wh[0][b + 0] * hv.x; a0.y += wh[0][b + 1] * hv.y; a0.z += wh[0][b + 2] * hv.z; a0.w += wh[0][b + 3] * hv.w;
      a1.x += wh[1][b + 0] * hv.x; a1.y += wh[1][b + 1] * hv.y; a1.z += wh[1][b + 2] * hv.z; a1.w += wh[1][b + 3] * hv.w;
      a2.x += wh[2][b + 0] * hv.x; a2.y += wh[2][b + 1] * hv.y; a2.z += wh[2][b + 2] * hv.z; a2.w += wh[2][b + 3] * hv.w;
      a3.x += wh[3][b + 0] * hv.x; a3.y += wh[3][b + 1] * hv.y; a3.z += wh[3][b + 2] * hv.z; a3.w += wh[3][b + 3] * hv.w;
    }

    // ---- reduce 8 kc-chunks inside each wave (lane bits 3,4,5), partials to LDS ----
    float r0 = (a0.x + a0.y) + (a0.z + a0.w);
    float r1 = (a1.x + a1.y) + (a1.z + a1.w);
    float r2 = (a2.x + a2.y) + (a2.z + a2.w);
    float r3 = (a3.x + a3.y) + (a3.z + a3.w);
#pragma unroll
    for (int m = 8; m < 64; m <<= 1) {
      r0 += __shfl_xor(r0, m); r1 += __shfl_xor(r1, m);
      r2 += __shfl_xor(r2, m); r3 += __shfl_xor(r3, m);
    }
    if ((tid & 63) < 8)
      *(float4*)(partbuf + (tid >> 6) * 32 + j * 4) = make_float4(r0, r1, r2, r3);
    __syncthreads();   // the ONLY per-step barrier

    // ---- wave0: gather, fast activate, [free drain] publish, deferred resets ----
    if (tid < 8) {
      float s0 = 0.f, s1 = 0.f, s2 = 0.f, s3 = 0.f;
#pragma unroll
      for (int w = 0; w < 8; ++w) {
        const float4 pv = *(const float4*)(partbuf + w * 32 + tid * 4);
        s0 += pv.x; s1 += pv.y; s2 += pv.z; s3 += pv.w;
      }
      const float gi = s0 + bg0, gf = s1 + bg1, gg = s2 + bg2, go = s3 + bg3;
      const float cN = sigf(gf) * c_reg + sigf(gi) * tanhf_fast(gg);
      c_reg = cN;
      const float hN = sigf(go) * tanhf_fast(cN);
      // drains LAST step's publish+reset stores (issued ~1 step ago -> free); orders
      // step t-1's resets before this publish becomes observable.
      asm volatile("s_waitcnt vmcnt(0)" ::: "memory");
      float* const pub = hbuf + (size_t)(((t + 1) & 3) * NCPY) * EMB + jbase + tid;
#pragma unroll
      for (int c = 0; c < NCPY; ++c)
        __hip_atomic_store(pub + (size_t)c * EMB, hN,
                           __ATOMIC_RELAXED, __HIP_MEMORY_SCOPE_AGENT);
      float* const rearm = hbuf + (size_t)(((t + 3) & 3) * NCPY) * EMB + jbase + tid;
#pragma unroll
      for (int c = 0; c < NCPY; ++c)
        __hip_atomic_store(rearm + (size_t)c * EMB, QNAN,
                           __ATOMIC_RELAXED, __HIP_MEMORY_SCOPE_AGENT);
    }
    xcur = xnext;
  }
}

// ---------------- persistent decoder: R9 structure + no-dup polls + poll backoff ----------------
// 16 WGs x 512 thr. WG w owns c-indices [32w, 32w+32). Wfold 4x30 = 120 floats/thread pinned.
// hraw ring 4 slots x NDCPY(4) copies x 512 f32 (NaN = empty). Consumer WG polls copy wg&3.
// NEW vs R9: only lanes l<30 of each wave poll (granule 30*wv+l); lanes >=30 skip — the
// dl2 region a wave's MAC reads is written by lanes l<30 of the SAME wave, so same-wave
// DS ordering still covers it (no barrier needed, divergence reconverges before the MAC).
// Poll backoff s_sleep(1). Tail/publish/reset byte-identical to R9.
__global__ __launch_bounds__(512) __attribute__((amdgpu_waves_per_eu(2, 2))) void dec_kernel(
    const float* __restrict__ dWih, const float* __restrict__ Wfold,
    const float* __restrict__ btot, const float* __restrict__ henc,
    float* __restrict__ hraw, float* __restrict__ out) {
  const int tid = threadIdx.x;
  const int wg  = blockIdx.x;
  const int j   = tid & 31;
  const int kc  = tid >> 5;          // 0..15 (wave-local: wave v has kc in {2v, 2v+1})
  const int idx = wg * 32 + j;
  const bool valid = (idx < INP);
  const int id0 = valid ? idx : 0;
  const int l   = tid & 63;
  const int wv  = tid >> 6;
  const int mycpy = wg & (NDCPY - 1);

  float wd[4][30];
#pragma unroll
  for (int g = 0; g < 4; ++g) {
    const float* wp = Wfold + (size_t)(g * INP + id0) * 480 + kc * 30;
#pragma unroll
    for (int q = 0; q < 15; ++q) {
      const float2 v = valid ? *(const float2*)(wp + 2 * q) : make_float2(0.0f, 0.0f);
      wd[g][q * 2 + 0] = v.x; wd[g][q * 2 + 1] = v.y;
    }
  }
#pragma unroll
  for (int g = 0; g < 4; ++g)
#pragma unroll
    for (int q = 0; q < 30; ++q) PIN(wd[g][q]);

  const float bg0 = valid ? btot[0 * INP + idx] : 0.0f;
  const float bg1 = valid ? btot[1 * INP + idx] : 0.0f;
  const float bg2 = valid ? btot[2 * INP + idx] : 0.0f;
  const float bg3 = valid ? btot[3 * INP + idx] : 0.0f;
  float c_reg = 0.0f;

  __shared__ float2 dl2[240];      // 480 floats: staged hraw, wave-local regions
  __shared__ float  partbuf[1024]; // 8 waves x 32 j x 4 gates

  for (int t = 0; t < SEQ; ++t) {
    if (t > 0) {
      // ---- poll-stage hraw_t from MY copy: only lanes l<30, wave-local granules ----
      if (l < 30) {
        const int gidx = 30 * wv + l;
        const f32x2* gp = (const f32x2*)(hraw + (size_t)((t & 3) * NDCPY + mycpy) * 512) + gidx;
        f32x2 g2;
        for (;;) {
          g2 = mall8(gp);
          if ((g2.x == g2.x) & (g2.y == g2.y)) break;
          __builtin_amdgcn_s_sleep(1);
        }
        dl2[gidx] = make_float2(g2.x, g2.y);
      }
      // reconverged; same-wave DS ordering covers dl2 region [30*wv, 30*wv+30)
    }

    float2 acc0 = make_float2(0, 0), acc1 = acc0, acc2 = acc0, acc3 = acc0;
    if (t == 0) {
      if (valid) {
#pragma unroll 4
        for (int q = 0; q < 32; ++q) {
          const float4 hv = *(const float4*)(henc + kc * 128 + 4 * q);
          const float4 w0 = *(const float4*)(dWih + (size_t)(0 * INP + idx) * EMB + kc * 128 + 4 * q);
          const float4 w1 = *(const float4*)(dWih + (size_t)(1 * INP + idx) * EMB + kc * 128 + 4 * q);
          const float4 w2 = *(const float4*)(dWih + (size_t)(2 * INP + idx) * EMB + kc * 128 + 4 * q);
          const float4 w3 = *(const float4*)(dWih + (size_t)(3 * INP + idx) * EMB + kc * 128 + 4 * q);
          acc0.x += w0.x * hv.x + w0.z * hv.z; acc0.y += w0.y * hv.y + w0.w * hv.w;
          acc1.x += w1.x * hv.x + w1.z * hv.z; acc1.y += w1.y * hv.y + w1.w * hv.w;
          acc2.x += w2.x * hv.x + w2.z * hv.z; acc2.y += w2.y * hv.y + w2.w * hv.w;
          acc3.x += w3.x * hv.x + w3.z * hv.z; acc3.y += w3.y * hv.y + w3.w * hv.w;
        }
      }
    } else {
#pragma unroll
      for (int q = 0; q < 15; ++q) {
        const float2 hv = dl2[kc * 15 + q];
        acc0.x += wd[0][q * 2] * hv.x; acc0.y += wd[0][q * 2 + 1] * hv.y;
        acc1.x += wd[1][q * 2] * hv.x; acc1.y += wd[1][q * 2 + 1] * hv.y;
        acc2.x += wd[2][q * 2] * hv.x; acc2.y += wd[2][q * 2 + 1] * hv.y;
        acc3.x += wd[3][q * 2] * hv.x; acc3.y += wd[3][q * 2 + 1] * hv.y;
      }
    }
    float r0 = acc0.x + acc0.y, r1 = acc1.x + acc1.y, r2 = acc2.x + acc2.y, r3 = acc3.x + acc3.y;
    r0 += __shfl_xor(r0, 32); r1 += __shfl_xor(r1, 32);
    r2 += __shfl_xor(r2, 32); r3 += __shfl_xor(r3, 32);
    if ((tid & 63) < 32)
      *(float4*)(partbuf + (tid >> 6) * 128 + (tid & 31) * 4) = make_float4(r0, r1, r2, r3);
    __syncthreads();   // the ONLY per-step barrier

    if (tid < 32) {
      const int ix = wg * 32 + tid;
      float s0 = 0.f, s1 = 0.f, s2 = 0.f, s3 = 0.f;
#pragma unroll
      for (int w = 0; w < 8; ++w) {
        const float4 pv = *(const float4*)(partbuf + w * 128 + tid * 4);
        s0 += pv.x; s1 += pv.y; s2 += pv.z; s3 += pv.w;
      }
      const float gi = s0 + bg0, gf = s1 + bg1, gg = s2 + bg2, go = s3 + bg3;
      const float cN = sigf(gf) * c_reg + sigf(gi) * tanhf_fast(gg);
      c_reg = cN;
      const float hrN = sigf(go) * tanhf_fast(cN);
      // drains LAST step's publish+reset+out stores (issued ~1 step ago -> free)
      asm volatile("s_waitcnt vmcnt(0)" ::: "memory");
      if (ix < 480) {
        const float pv = (ix < INP) ? hrN : 0.0f;
#pragma unroll
        for (int c = 0; c < NDCPY; ++c)
          __hip_atomic_store(hraw + (size_t)(((t + 1) & 3) * NDCPY + c) * 512 + ix, pv,
                             __ATOMIC_RELAXED, __HIP_MEMORY_SCOPE_AGENT);
      }
      if (ix < INP) out[(size_t)(SEQ - 1 - t) * INP + ix] = cN;
      // deferred re-arm of slot (t+3)&3, all copies
      if (ix < 480) {
#pragma unroll
        for (int c = 0; c < NDCPY; ++c)
          __hip_atomic_store(hraw + (size_t)(((t + 3) & 3) * NDCPY + c) * 512 + ix, QNAN,
                             __ATOMIC_RELAXED, __HIP_MEMORY_SCOPE_AGENT);
      }
    }
  }
}

// ---------------- row softmax in-place on d_out (4096 x 457) ----------------
__global__ __launch_bounds__(512) void softmax_kernel(float* __restrict__ out) {
  const int row = blockIdx.x;
  const int tid = threadIdx.x;
  __shared__ float red[512];
  float* rp = out + (size_t)row * INP;
  float v = (tid < INP) ? rp[tid] : -INFINITY;
  red[tid] = v;
  __syncthreads();
#pragma unroll
  for (int off = 256; off > 0; off >>= 1) {
    if (tid < off) red[tid] = fmaxf(red[tid], red[tid + off]);
    __syncthreads();
  }
  const float m = red[0];
  __syncthreads();
  const float e = (tid < INP) ? expf(v - m) : 0.0f;
  red[tid] = e;
  __syncthreads();
#pragma unroll
  for (int off = 256; off > 0; off >>= 1) {
    if (tid < off) red[tid] = red[tid] + red[tid + off];
    __syncthreads();
  }
  const float s = red[0];
  if (tid < INP) rp[tid] = e / s;
}

extern "C" void kernel_launch(void* const* d_in, const int* in_sizes, int n_in,
                              void* d_out, int out_size, void* d_ws, size_t ws_size,
                              hipStream_t stream) {
  const float* x    = (const float*)d_in[0];
  const float* eWih = (const float*)d_in[1];
  const float* eWhh = (const float*)d_in[2];
  const float* ebih = (const float*)d_in[3];
  const float* ebhh = (const float*)d_in[4];
  const float* dWih = (const float*)d_in[5];
  const float* dWhh = (const float*)d_in[6];
  const float* dbih = (const float*)d_in[7];
  const float* dbhh = (const float*)d_in[8];
  const float* dWhr = (const float*)d_in[9];
  float* out = (float*)d_out;
  char* ws = (char*)d_ws;

  // ws layout (same as R9):
  // [0, 262144):         hbuf ring: 4 slots x NCPY(8) copies x 2048 f32. Slot0 (all copies)
  //                      pre-zeroed = h_0; rest NaN. h_enc = h_4096 lands in slot0, copy0.
  // [262144, 294912):    hraw ring: 4 slots x NDCPY(4) copies x 512 f32, NaN-init.
  // [294912, 327680):    bsum (4*EMB f32)
  // [327680, 335872):    btot (4*INP f32, padded)
  // [335872, +3.51MB):   Wfold 1828x480
  float* hbuf  = (float*)(ws + 0);
  float* hraw  = (float*)(ws + 262144);
  float* bsum  = (float*)(ws + 294912);
  float* btot  = (float*)(ws + 327680);
  float* Wfold = (float*)(ws + 335872);

  hipMemsetAsync(ws, 0xFF, 294912, stream);   // hbuf (all slots/copies) + hraw -> NaN sentinel
  hipMemsetAsync(ws, 0x00, 65536, stream);    // hbuf slot0, all 8 copies -> h_0 = 0
  bias_kernel<<<40, 256, 0, stream>>>(ebih, ebhh, dbih, dbhh, bsum, btot);
  fold_gemm<<<dim3(8, 29), 256, 0, stream>>>(dWih, dWhh, dWhr, Wfold);
  enc_kernel<<<NWG_E, 512, 0, stream>>>(x, eWih, eWhh, bsum, hbuf);
  dec_kernel<<<NWG_D, 512, 0, stream>>>(dWih, Wfold, btot, hbuf, hraw, out);
  softmax_kernel<<<SEQ, 512, 0, stream>>>(out);
}